// Round 6
// baseline (26.808 us; speedup 1.0000x reference)
//
#include <hip/hip_runtime.h>
#include <hip/hip_bf16.h>

// Problem constants: B=16, S=2048, D=512
// inputs: x [B,S,D] f32, input_ids [B,S] int32, start_token_id int scalar,
//         control_emb [4, D] f32, sequence_emb [1003, D] f32
// output: [B,S,D] f32

#define S_LEN 2048
#define D4 128                    // float4 per row (D=512)
#define SEQ_START 4
#define NUM_SEQ 1003
#define CS 64                     // positions (rows) per block
#define NCHUNK (S_LEN / CS)       // 32 chunks per batch row
#define THREADS 512               // 8 waves
#define ITERS 16                  // rows per wave (16 rows x half-width each)
#define PF 8                      // rolling prefetch depth (x AND emb)

typedef float f4 __attribute__((ext_vector_type(4)));
typedef int   i4 __attribute__((ext_vector_type(4)));

// Barrier-free fused kernel, dual 8-deep register prefetch (x + embedding).
// Wave w owns rows [16*(w>>1), 16*(w>>1)+16), column half (w&1).
// No LDS, no __syncthreads.
__global__ void __launch_bounds__(THREADS, 4)
alpe_kernel(const f4* __restrict__ x,
            const f4* __restrict__ ctrl,
            const f4* __restrict__ seq,
            const int* __restrict__ ids,
            const int* __restrict__ start_tok,
            f4* __restrict__ out) {
    const int b   = blockIdx.x / NCHUNK;
    const int cid = blockIdx.x % NCHUNK;
    const int chunk_start = cid * CS;
    const int t = threadIdx.x;
    const int w = t >> 6;           // wave id 0..7
    const int l = t & 63;           // lane
    const int wr   = w >> 1;        // row group 0..3
    const int half = w & 1;         // column half
    const int col  = (half << 6) | l;   // f4 column 0..127
    const int st = *start_tok;
    const int* __restrict__ idrow = ids + b * S_LEN;

    // ---- ids first (they gate the scan) ----
    const int myid = idrow[chunk_start + l];

    // incremental prefix marker max over [0, chunk_start)
    int pm = -1;
    if (chunk_start > 0) {
        #pragma unroll
        for (int r = 0; r < 8; ++r) {
            const i4 v = *(const i4*)&idrow[r * 256 + l * 4];
            #pragma unroll
            for (int k = 0; k < 4; ++k) {
                const int j = r * 256 + l * 4 + k;
                if (v[k] == st && j >= SEQ_START && j < chunk_start)
                    pm = max(pm, j);
            }
        }
        #pragma unroll
        for (int off = 32; off >= 1; off >>= 1)
            pm = max(pm, __shfl_xor(pm, off));
    }

    // ---- x prefetch issued before the scan chain completes ----
    const size_t base4 = (size_t)(b * S_LEN + chunk_start) * D4;
    f4 xp[PF];
    #pragma unroll
    for (int i = 0; i < PF; ++i)
        xp[i] = x[base4 + (size_t)(16 * wr + i) * D4 + col];

    // ---- inclusive max-scan over the chunk's own 64 positions ----
    const int p = chunk_start + l;
    int mk = (myid == st && p >= SEQ_START) ? p : -1;
    #pragma unroll
    for (int off = 1; off < 64; off <<= 1) {
        const int o = __shfl_up(mk, off);
        if (l >= off) mk = max(mk, o);
    }
    const int last = max(mk, pm);
    int mycode;                       // code for row (chunk_start + l)
    if (last >= 0) {
        const int rel = p - last;
        mycode = (rel < NUM_SEQ) ? rel : -1;
    } else {
        mycode = (p < SEQ_START) ? (-2 - p) : -1;
    }

    // ---- embedding prefetch (8 deep), codes via shfl broadcast ----
    f4 ep[PF];
    #pragma unroll
    for (int i = 0; i < PF; ++i) {
        const int c = __shfl(mycode, 16 * wr + i);
        f4 e = (f4){0.f, 0.f, 0.f, 0.f};
        if (c >= 0)        e = seq[c * D4 + col];
        else if (c <= -2)  e = ctrl[(-2 - c) * D4 + col];
        ep[i] = e;
    }

    // ---- streaming add, dual rolling prefetch ----
    #pragma unroll
    for (int it = 0; it < ITERS; ++it) {
        const int row = 16 * wr + it;
        const f4 xv = xp[it & (PF - 1)];
        const f4 ev = ep[it & (PF - 1)];
        if (it + PF < ITERS) {
            xp[it & (PF - 1)] = x[base4 + (size_t)(row + PF) * D4 + col];
            const int c2 = __shfl(mycode, row + PF);
            f4 e = (f4){0.f, 0.f, 0.f, 0.f};
            if (c2 >= 0)       e = seq[c2 * D4 + col];
            else if (c2 <= -2) e = ctrl[(-2 - c2) * D4 + col];
            ep[it & (PF - 1)] = e;
        }
        out[base4 + (size_t)row * D4 + col] = xv + ev;
    }
}

extern "C" void kernel_launch(void* const* d_in, const int* in_sizes, int n_in,
                              void* d_out, int out_size, void* d_ws, size_t ws_size,
                              hipStream_t stream) {
    const float* x         = (const float*)d_in[0];
    const int*   input_ids = (const int*)d_in[1];
    const int*   start_tok = (const int*)d_in[2];
    const float* ctrl      = (const float*)d_in[3];
    const float* seq       = (const float*)d_in[4];
    float*       out       = (float*)d_out;

    const int B = in_sizes[1] / S_LEN;          // 16
    const int grid = B * NCHUNK;                // 512 blocks

    alpe_kernel<<<grid, THREADS, 0, stream>>>(
        (const f4*)x, (const f4*)ctrl, (const f4*)seq,
        input_ids, start_tok, (f4*)out);
}

// Round 7
// 25.751 us; speedup vs baseline: 1.0410x; 1.0410x over previous
//
#include <hip/hip_runtime.h>
#include <hip/hip_bf16.h>

// Problem constants: B=16, S=2048, D=512
// inputs: x [B,S,D] f32, input_ids [B,S] int32, start_token_id int scalar,
//         control_emb [4, D] f32, sequence_emb [1003, D] f32
// output: [B,S,D] f32
//
// REVERT to R5 (best measured: 25.5 us, absmax 0). R6's dual embed-prefetch
// regressed (26.8): the seq gather is L2-resident and already latency-hidden
// by TLP; extra VGPR + shfl serialization cost more than it saved.
//
// Roofline note: harness fills (256 MB) run between graph replays, flushing
// L2/L3 -> mandatory HBM traffic ~145 MB (x 64 + out 64 + seq 2x8 XCD = 16
// + ids ~1). At ~6.0-6.3 TB/s mixed-stream + ~1.5 us launch, floor is
// ~24.5-25.5 us. This kernel sits inside that band.

#define S_LEN 2048
#define D4 128                    // float4 per row (D=512)
#define SEQ_START 4
#define NUM_SEQ 1003
#define CS 64                     // positions (rows) per block
#define NCHUNK (S_LEN / CS)       // 32 chunks per batch row
#define THREADS 512               // 8 waves
#define ITERS ((CS * D4) / THREADS)   // 16 f4 per thread
#define PF 8                      // x prefetch depth (registers)
#define IDR 8                     // ids rounds: 8 * 256 = 2048 ids

typedef float f4 __attribute__((ext_vector_type(4)));
typedef int   i4 __attribute__((ext_vector_type(4)));

// Barrier-free fused kernel. Each wave independently computes all 64 codes
// for the block's chunk in registers (redundant across the 8 waves; ids data
// is L1/L2-hot), while an 8-deep register prefetch of x hides HBM latency.
// No LDS, no __syncthreads.
__global__ void __launch_bounds__(THREADS, 4)
alpe_kernel(const f4* __restrict__ x,
            const f4* __restrict__ ctrl,
            const f4* __restrict__ seq,
            const int* __restrict__ ids,
            const int* __restrict__ start_tok,
            f4* __restrict__ out) {
    const int b   = blockIdx.x / NCHUNK;
    const int cid = blockIdx.x % NCHUNK;
    const int chunk_start = cid * CS;
    const int t = threadIdx.x;
    const int w = t >> 6;          // wave id 0..7
    const int l = t & 63;          // lane
    const int st = *start_tok;
    const int* __restrict__ idrow = ids + b * S_LEN;

    // ---- issue ids loads FIRST (they gate the scan; x loads come after so
    // waiting on ids does not drain the x queue) ----
    const int myid = idrow[chunk_start + l];          // my chunk position's id
    i4 idv[IDR];
    #pragma unroll
    for (int r = 0; r < IDR; ++r)
        idv[r] = *(const i4*)&idrow[r * 256 + l * 4];  // full-row prefix, static

    // ---- issue x prefetch (PF deep) ----
    const size_t base4 = (size_t)(b * S_LEN + chunk_start) * D4;
    f4 xp[PF];
    #pragma unroll
    for (int i = 0; i < PF; ++i)
        xp[i] = x[base4 + i * THREADS + t];

    // ---- prefix marker max over [0, chunk_start) ----
    int pm = -1;
    #pragma unroll
    for (int r = 0; r < IDR; ++r) {
        #pragma unroll
        for (int k = 0; k < 4; ++k) {
            const int j = r * 256 + l * 4 + k;
            const int id = idv[r][k];
            if (id == st && j >= SEQ_START && j < chunk_start) pm = max(pm, j);
        }
    }
    #pragma unroll
    for (int off = 32; off >= 1; off >>= 1)
        pm = max(pm, __shfl_xor(pm, off));

    // ---- inclusive max-scan over the chunk's own 64 positions ----
    const int p = chunk_start + l;
    int mk = (myid == st && p >= SEQ_START) ? p : -1;
    #pragma unroll
    for (int off = 1; off < 64; off <<= 1) {
        const int o = __shfl_up(mk, off);
        if (l >= off) mk = max(mk, o);
    }
    const int last = max(mk, pm);
    int mycode;                       // code for row (chunk_start + l)
    if (last >= 0) {
        const int rel = p - last;
        mycode = (rel < NUM_SEQ) ? rel : -1;
    } else {
        mycode = (p < SEQ_START) ? (-2 - p) : -1;
    }

    // ---- streaming add: wave w, iteration it covers row 4*it + (w>>1),
    // half (w&1) of the 128 f4 columns ----
    const int d4w = ((w & 1) << 6) | l;       // my f4 column in the row
    const int rsel = w >> 1;                  // row offset within groups of 4
    #pragma unroll
    for (int it = 0; it < ITERS; ++it) {
        const f4 xv = xp[it & (PF - 1)];
        if (it + PF < ITERS)
            xp[it & (PF - 1)] = x[base4 + (it + PF) * THREADS + t];
        const int code = __shfl(mycode, 4 * it + rsel);   // wave-uniform
        f4 e = (f4){0.f, 0.f, 0.f, 0.f};
        if (code >= 0) {
            e = seq[code * D4 + d4w];
        } else if (code <= -2) {
            e = ctrl[(-2 - code) * D4 + d4w];
        }
        out[base4 + it * THREADS + t] = xv + e;
    }
}

extern "C" void kernel_launch(void* const* d_in, const int* in_sizes, int n_in,
                              void* d_out, int out_size, void* d_ws, size_t ws_size,
                              hipStream_t stream) {
    const float* x         = (const float*)d_in[0];
    const int*   input_ids = (const int*)d_in[1];
    const int*   start_tok = (const int*)d_in[2];
    const float* ctrl      = (const float*)d_in[3];
    const float* seq       = (const float*)d_in[4];
    float*       out       = (float*)d_out;

    const int B = in_sizes[1] / S_LEN;          // 16
    const int grid = B * NCHUNK;                // 512 blocks

    alpe_kernel<<<grid, THREADS, 0, stream>>>(
        (const f4*)x, (const f4*)ctrl, (const f4*)seq,
        input_ids, start_tok, (f4*)out);
}